// Round 1
// baseline (97.571 us; speedup 1.0000x reference)
//
#include <hip/hip_runtime.h>

#define BATCH 256
#define NCLS  1019
#define GRID  7
#define NOBJ  16
#define PLANE 49      // GRID*GRID
#define NCH   1024    // 5 + NCLS

__global__ __launch_bounds__(256) void yolo_loss_kernel(
    const float* __restrict__ outputs,    // [B, 1024, 7, 7]
    const float* __restrict__ boxes,      // [B, 16, 4]
    const int*   __restrict__ labels,     // [B, 16]  (1..C)
    const int*   __restrict__ coords,     // [B, 16, 2] (x, y)
    const float* __restrict__ obj_matrix, // [B, 49]
    float* __restrict__ out)              // [1]
{
    const int b    = blockIdx.x;
    const int t    = threadIdx.x;
    const int lane = t & 63;
    const int wave = t >> 6;

    __shared__ int   s_pos[NOBJ];
    __shared__ int   s_cl[NOBJ];
    __shared__ float s_se[NOBJ];   // sum of exp per object
    __shared__ float s_tl[NOBJ];   // target-class logit per object
    __shared__ float s_acc;

    const float* ob = outputs + (size_t)b * NCH * PLANE;

    if (t == 0) s_acc = 0.0f;
    if (t < NOBJ) {
        int x = coords[(b * NOBJ + t) * 2 + 0];
        int y = coords[(b * NOBJ + t) * 2 + 1];
        s_pos[t] = y * GRID + x;
        s_cl[t]  = labels[b * NOBJ + t] - 1;
        s_se[t]  = 0.0f;
    }
    __syncthreads();

    // ---------- class CE: sum(exp) over 1019 channels per object ----------
    int pos[NOBJ];
#pragma unroll
    for (int o = 0; o < NOBJ; ++o) pos[o] = s_pos[o];
    int cls[NOBJ];
#pragma unroll
    for (int o = 0; o < NOBJ; ++o) cls[o] = s_cl[o];

    float se[NOBJ];
#pragma unroll
    for (int o = 0; o < NOBJ; ++o) se[o] = 0.0f;

    for (int c = t; c < NCLS; c += 256) {
        const float* plane = ob + (size_t)(5 + c) * PLANE;
#pragma unroll
        for (int o = 0; o < NOBJ; ++o) {
            float v = plane[pos[o]];
            se[o] += __expf(v);
            if (c == cls[o]) s_tl[o] = v;   // exactly one writer per o
        }
    }
#pragma unroll
    for (int o = 0; o < NOBJ; ++o) {
        float v = se[o];
#pragma unroll
        for (int off = 32; off > 0; off >>= 1)
            v += __shfl_xor(v, off, 64);
        if (lane == 0) atomicAdd(&s_se[o], v);
    }

    // ---------- objectness CE (wave 0) ----------
    if (wave == 0) {
        float l = (lane < PLANE) ? ob[lane] : 0.0f;
        float e = (lane < PLANE) ? __expf(l) : 0.0f;
        float s = e;
#pragma unroll
        for (int off = 32; off > 0; off >>= 1)
            s += __shfl_xor(s, off, 64);
        float lse = __logf(s);
        float m = (lane < PLANE) ? obj_matrix[b * PLANE + lane] : 0.0f;
        float contrib = (lane < PLANE) ? -m * (l - lse) : 0.0f;
#pragma unroll
        for (int off = 32; off > 0; off >>= 1)
            contrib += __shfl_xor(contrib, off, 64);
        if (lane == 0) atomicAdd(&s_acc, contrib);
    }

    // ---------- bb MSE (wave 1) ----------
    if (wave == 1) {
        int o = lane >> 2, k = lane & 3;   // 64 lanes = 16 objects x 4 coords
        float pred = ob[(size_t)(1 + k) * PLANE + s_pos[o]];
        float tb   = boxes[(b * NOBJ + o) * 4 + k];
        float tgt  = rintf(tb / 448.0f * 10.0f) * 0.1f;  // round-half-even like jnp.round
        float d    = tgt - pred;
        float sq   = d * d;
#pragma unroll
        for (int off = 32; off > 0; off >>= 1)
            sq += __shfl_xor(sq, off, 64);
        if (lane == 0) atomicAdd(&s_acc, sq);
    }

    __syncthreads();

    // ---------- finalize class CE ----------
    if (t < NOBJ) {
        float ce = __logf(s_se[t]) - s_tl[t];
        atomicAdd(&s_acc, ce);
    }
    __syncthreads();

    if (t == 0) {
        atomicAdd(out, s_acc * (1.0f / (float)BATCH));
    }
}

extern "C" void kernel_launch(void* const* d_in, const int* in_sizes, int n_in,
                              void* d_out, int out_size, void* d_ws, size_t ws_size,
                              hipStream_t stream) {
    const float* outputs    = (const float*)d_in[0];
    const float* boxes      = (const float*)d_in[1];
    const int*   labels     = (const int*)d_in[2];
    const int*   coords     = (const int*)d_in[3];
    const float* obj_matrix = (const float*)d_in[4];
    float* out = (float*)d_out;

    hipMemsetAsync(out, 0, sizeof(float), stream);
    yolo_loss_kernel<<<BATCH, 256, 0, stream>>>(outputs, boxes, labels, coords,
                                                obj_matrix, out);
}